// Round 5
// baseline (235.000 us; speedup 1.0000x reference)
//
#include <hip/hip_runtime.h>

typedef __attribute__((ext_vector_type(8))) short bh8;   // 8 bf16
typedef __attribute__((ext_vector_type(4))) float fx4;   // mfma acc

__device__ __forceinline__ unsigned short f2bf(float f) {
  unsigned u = __float_as_uint(f);
  u += 0x7FFFu + ((u >> 16) & 1u);     // RNE
  return (unsigned short)(u >> 16);
}

__device__ __forceinline__ bh8 pack8(float4 u, float4 v) {
  bh8 r;
  r[0] = (short)f2bf(u.x); r[1] = (short)f2bf(u.y);
  r[2] = (short)f2bf(u.z); r[3] = (short)f2bf(u.w);
  r[4] = (short)f2bf(v.x); r[5] = (short)f2bf(v.y);
  r[6] = (short)f2bf(v.z); r[7] = (short)f2bf(v.w);
  return r;
}

// ---------------- K0: BT2[b][kc][o][ki] = bf16 B^T[b][o][k=kc*32+ki] ---------------
// Fragment-contiguous layout: a k1 wave's B-frag load (o-tile j, step s) is 1KB
// contiguous. grid 256 (8 b x 32 chunks of 32 m), block 256. Also zeroes gstat.
__global__ void __launch_bounds__(256) k0_bt(const float* __restrict__ x,
    const float* __restrict__ W1, const float* __restrict__ W2,
    unsigned* __restrict__ btw, float* __restrict__ gstat) {
  __shared__ float xl[32][32];     // 4 KB
  __shared__ float wl[96][64];     // 24 KB, wl[k][o]
  int t = threadIdx.x;
  int bid = blockIdx.x;
  int b = bid >> 5, c = bid & 31;

  if (bid == 0 && t < 128) gstat[t] = 0.f;   // zero BN accumulators (ws is poisoned)

  for (int i = t; i < 3072; i += 256) {       // coalesced W loads
    int r = i / 96, k = i - r * 96;
    wl[k][r]      = W1[i];
    wl[k][r + 32] = W2[i];
  }
  const float4* xs = (const float4*)(x + (size_t)(b * 1024 + c * 32) * 32);
  ((float4*)xl)[t] = xs[t];
  __syncthreads();

  int o = t & 63;
  int q = t >> 6;
  int m0 = q * 8;
  float acc[8][3];
#pragma unroll
  for (int m = 0; m < 8; ++m) acc[m][0] = acc[m][1] = acc[m][2] = 0.f;
#pragma unroll
  for (int f4 = 0; f4 < 8; ++f4) {
    float wv[3][4];
#pragma unroll
    for (int u = 0; u < 4; ++u) {
      int f = f4 * 4 + u;
      wv[0][u] = wl[f][o];
      wv[1][u] = wl[32 + f][o];
      wv[2][u] = wl[64 + f][o];
    }
#pragma unroll
    for (int m = 0; m < 8; ++m) {
      float4 xv = *(const float4*)&xl[m0 + m][f4 * 4];
#pragma unroll
      for (int j = 0; j < 3; ++j) {
        acc[m][j] = fmaf(xv.x, wv[j][0], acc[m][j]);
        acc[m][j] = fmaf(xv.y, wv[j][1], acc[m][j]);
        acc[m][j] = fmaf(xv.z, wv[j][2], acc[m][j]);
        acc[m][j] = fmaf(xv.w, wv[j][3], acc[m][j]);
      }
    }
  }
  unsigned pk[12];
#pragma unroll
  for (int i = 0; i < 12; ++i) {
    unsigned short lo = f2bf(acc[(2 * i) / 3][(2 * i) % 3]);
    unsigned short hi = f2bf(acc[(2 * i + 1) / 3][(2 * i + 1) % 3]);
    pk[i] = (unsigned)lo | ((unsigned)hi << 16);
  }
  // this thread's 24 k's: k = 3*(c*32 + q*8) + {0..23}, pairs are k-even -> uint
  int kbase = 96 * c + 24 * q;
#pragma unroll
  for (int i = 0; i < 12; ++i) {
    int kg = kbase + 2 * i;
    int kc = kg >> 5, ki = kg & 31;
    btw[((b * 96 + kc) * 64 + o) * 16 + (ki >> 1)] = pk[i];
  }
}

// ---------------- K1: LDS-free barrier-free GEMM, fragment-layout B ----------------
// grid 1024 (128 mtiles x 8 ksplits), block 256 = 4 independent waves (16 rows each,
// all 64 o). A: direct coalesced f32 loads. B: 1KB-contiguous frag loads (L2-hit).
__global__ void __launch_bounds__(256) k1_gemm(const float* __restrict__ A,
    const unsigned short* __restrict__ BT2, float* __restrict__ parts) {
  int t = threadIdx.x;
  int w = t >> 6, l = t & 63;
  int lr = l & 15, lg = l >> 4;
  int bid = blockIdx.x;
  int ks = bid & 7, mtb = bid >> 3;          // mtb 0..127
  int b = mtb >> 4;
  int r0 = mtb * 64 + w * 16;
  const float* ap = A + (size_t)(r0 + lr) * 3072 + ks * 384 + lg * 8;
  // BT2 elem idx: ((b*96 + kc)*64 + o)*32 + ki ; kc = ks*12 + s ; o = j*16+lr ; ki = lg*8
  const unsigned short* bp = BT2 + ((size_t)(b * 96 + ks * 12) * 64 + lr) * 32 + lg * 8;

  fx4 acc0 = {0.f,0.f,0.f,0.f}, acc1 = {0.f,0.f,0.f,0.f};
  fx4 acc2 = {0.f,0.f,0.f,0.f}, acc3 = {0.f,0.f,0.f,0.f};

#define LOADA_(s, ra, rb) { ra = *(const float4*)(ap + (s) * 32); \
                            rb = *(const float4*)(ap + (s) * 32 + 4); }
#define LOADB_(s, c0, c1, c2, c3) { \
    c0 = *(const bh8*)(bp + (s) * 2048); \
    c1 = *(const bh8*)(bp + (s) * 2048 + 512); \
    c2 = *(const bh8*)(bp + (s) * 2048 + 1024); \
    c3 = *(const bh8*)(bp + (s) * 2048 + 1536); }
#define STEP_(ra, rb, c0, c1, c2, c3) { bh8 av = pack8(ra, rb); \
    acc0 = __builtin_amdgcn_mfma_f32_16x16x32_bf16(av, c0, acc0, 0, 0, 0); \
    acc1 = __builtin_amdgcn_mfma_f32_16x16x32_bf16(av, c1, acc1, 0, 0, 0); \
    acc2 = __builtin_amdgcn_mfma_f32_16x16x32_bf16(av, c2, acc2, 0, 0, 0); \
    acc3 = __builtin_amdgcn_mfma_f32_16x16x32_bf16(av, c3, acc3, 0, 0, 0); }

  float4 aA0, aA1, aB0, aB1;
  bh8 bA0, bA1, bA2, bA3, bB0, bB1, bB2, bB3;
  LOADA_(0, aA0, aA1); LOADB_(0, bA0, bA1, bA2, bA3);
  LOADA_(1, aB0, aB1); LOADB_(1, bB0, bB1, bB2, bB3);
#pragma unroll
  for (int s = 0; s < 12; s += 2) {
    STEP_(aA0, aA1, bA0, bA1, bA2, bA3);
    if (s + 2 < 12) { LOADA_(s + 2, aA0, aA1); LOADB_(s + 2, bA0, bA1, bA2, bA3); }
    STEP_(aB0, aB1, bB0, bB1, bB2, bB3);
    if (s + 3 < 12) { LOADA_(s + 3, aB0, aB1); LOADB_(s + 3, bB0, bB1, bB2, bB3); }
  }
#undef LOADA_
#undef LOADB_
#undef STEP_

  // D frag: col (lane&15) = o within o-tile, row = (lane>>4)*4 + reg
  float* pout = parts + ((size_t)ks * 8192 + (size_t)r0) * 64;
#pragma unroll
  for (int r = 0; r < 4; ++r) {
    int ro = (lg * 4 + r) * 64 + lr;
    pout[ro]      = acc0[r];
    pout[ro + 16] = acc1[r];
    pout[ro + 32] = acc2[r];
    pout[ro + 48] = acc3[r];
  }
}

// ---------------- K2: sum 8 partials + bias + relu -> z, atomic BN sums ------------
// grid 512 (16 rows each), block 256, one float4/thread/plane.
__global__ void __launch_bounds__(256) k2_red(const float* __restrict__ parts,
    const float* __restrict__ b1, const float* __restrict__ b2,
    float* __restrict__ z, float* __restrict__ gstat) {
  __shared__ float4 redA[4][16], redB[4][16];
  int t = threadIdx.x, bid = blockIdx.x;
  int w = t >> 6, l = t & 63;
  int o0 = (t & 15) * 4;
  float4 bias = (o0 < 32) ? ((const float4*)b1)[o0 >> 2]
                          : ((const float4*)b2)[(o0 - 32) >> 2];
  bool rl = (o0 < 32);
  const float4* p0 = (const float4*)parts;
  int i4 = bid * 256 + t;
  float4 v = p0[i4];
#pragma unroll
  for (int j = 1; j < 8; ++j) {
    float4 vj = p0[j * 131072 + i4];
    v.x += vj.x; v.y += vj.y; v.z += vj.z; v.w += vj.w;
  }
  v.x += bias.x; v.y += bias.y; v.z += bias.z; v.w += bias.w;
  if (rl) {
    v.x = fmaxf(v.x, 0.f); v.y = fmaxf(v.y, 0.f);
    v.z = fmaxf(v.z, 0.f); v.w = fmaxf(v.w, 0.f);
  }
  ((float4*)z)[i4] = v;
  float4 s1 = v;
  float4 s2 = make_float4(v.x * v.x, v.y * v.y, v.z * v.z, v.w * v.w);
#define RED_(c) { s1.c += __shfl_xor(s1.c, 16); s1.c += __shfl_xor(s1.c, 32); \
                  s2.c += __shfl_xor(s2.c, 16); s2.c += __shfl_xor(s2.c, 32); }
  RED_(x) RED_(y) RED_(z) RED_(w)
#undef RED_
  if (l < 16) { redA[w][l] = s1; redB[w][l] = s2; }
  __syncthreads();
  if (t < 16) {
    float4 S = redA[0][t], Q = redB[0][t];
#pragma unroll
    for (int wv = 1; wv < 4; ++wv) {
      float4 a = redA[wv][t], q = redB[wv][t];
      S.x += a.x; S.y += a.y; S.z += a.z; S.w += a.w;
      Q.x += q.x; Q.y += q.y; Q.z += q.z; Q.w += q.w;
    }
    int ob = t * 4;
    atomicAdd(&gstat[ob + 0], S.x); atomicAdd(&gstat[64 + ob + 0], Q.x);
    atomicAdd(&gstat[ob + 1], S.y); atomicAdd(&gstat[64 + ob + 1], Q.y);
    atomicAdd(&gstat[ob + 2], S.z); atomicAdd(&gstat[64 + ob + 2], Q.z);
    atomicAdd(&gstat[ob + 3], S.w); atomicAdd(&gstat[64 + ob + 3], Q.w);
  }
}

// ---------------- K4: redundant per-block scale/shift + normalize in place ---------
__global__ void __launch_bounds__(256) k4_norm(const float* __restrict__ gstat,
    const float* __restrict__ gamma, const float* __restrict__ beta,
    float* __restrict__ z) {
  __shared__ float2 sstat[64];
  int t = threadIdx.x, bid = blockIdx.x;
  if (t < 64) {
    float mean = gstat[t] * (1.0f / 8192.0f);
    float var = fmaxf(gstat[64 + t] * (1.0f / 8192.0f) - mean * mean, 0.f);
    float rstd = rsqrtf(var + 1e-5f);
    float scale = gamma[t] * rstd;
    sstat[t] = make_float2(scale, beta[t] - mean * scale);
  }
  __syncthreads();
  int i4 = bid * 256 + t;
  int o0 = (t & 15) * 4;
  float2 s0 = sstat[o0], s1 = sstat[o0 + 1], s2 = sstat[o0 + 2], s3 = sstat[o0 + 3];
  float4 v = ((const float4*)z)[i4];
  v.x = v.x * s0.x + s0.y;
  v.y = v.y * s1.x + s1.y;
  v.z = v.z * s2.x + s2.y;
  v.w = v.w * s3.x + s3.y;
  ((float4*)z)[i4] = v;
}

extern "C" void kernel_launch(void* const* d_in, const int* in_sizes, int n_in,
                              void* d_out, int out_size, void* d_ws, size_t ws_size,
                              hipStream_t stream) {
  const float* WW = (const float*)d_in[0];
  const float* x  = (const float*)d_in[1];
  const float* W1 = (const float*)d_in[2];
  const float* b1 = (const float*)d_in[3];
  const float* W2 = (const float*)d_in[4];
  const float* b2 = (const float*)d_in[5];
  const float* gamma = (const float*)d_in[6];
  const float* beta  = (const float*)d_in[7];

  unsigned short* bt = (unsigned short*)d_ws;                 //  3,145,728 B
  float* parts = (float*)((char*)d_ws + 3145728);             // 16,777,216 B
  float* gstat = (float*)((char*)d_ws + 3145728 + 16777216);  //        512 B
  float* z = (float*)d_out;

  hipLaunchKernelGGL(k0_bt,   dim3(256),  dim3(256), 0, stream, x, W1, W2,
                     (unsigned*)bt, gstat);
  hipLaunchKernelGGL(k1_gemm, dim3(1024), dim3(256), 0, stream, WW,
                     (const unsigned short*)bt, parts);
  hipLaunchKernelGGL(k2_red,  dim3(512),  dim3(256), 0, stream, parts, b1, b2, z, gstat);
  hipLaunchKernelGGL(k4_norm, dim3(512),  dim3(256), 0, stream, gstat, gamma, beta, z);
}

// Round 7
// 231.333 us; speedup vs baseline: 1.0159x; 1.0159x over previous
//
#include <hip/hip_runtime.h>

typedef __attribute__((ext_vector_type(8))) short bh8;   // 8 bf16
typedef __attribute__((ext_vector_type(4))) float fx4;   // mfma acc

__device__ __forceinline__ unsigned short f2bf(float f) {
  unsigned u = __float_as_uint(f);
  u += 0x7FFFu + ((u >> 16) & 1u);     // RNE
  return (unsigned short)(u >> 16);
}

__device__ __forceinline__ bh8 pack8(float4 u, float4 v) {
  bh8 r;
  r[0] = (short)f2bf(u.x); r[1] = (short)f2bf(u.y);
  r[2] = (short)f2bf(u.z); r[3] = (short)f2bf(u.w);
  r[4] = (short)f2bf(v.x); r[5] = (short)f2bf(v.y);
  r[6] = (short)f2bf(v.z); r[7] = (short)f2bf(v.w);
  return r;
}

__device__ __forceinline__ void async_g2l16(const void* g, void* l) {
  __builtin_amdgcn_global_load_lds(
      (const __attribute__((address_space(1))) unsigned int*)g,
      (__attribute__((address_space(3))) unsigned int*)l, 16, 0, 0);
}

// ---------------- K0: build BT as the pre-swizzled LDS image (r4 version) ----------
// BT_ws[(b*8+ks)*49152 + o*768 + (kbyte ^ ((o&7)<<4))] = bf16 B^T[b][o][ks*384+k]
// grid 256 (8 b x 32 chunks of 32 m), block 256. Contiguous uint4 stores.
__global__ void __launch_bounds__(256) k0_bt(const float* __restrict__ x,
    const float* __restrict__ W1, const float* __restrict__ W2,
    unsigned char* __restrict__ bt, float* __restrict__ gstat) {
  __shared__ float xl[32][32];     // 4 KB
  __shared__ float wl[96][64];     // 24 KB, wl[k][o]
  int t = threadIdx.x;
  int bid = blockIdx.x;
  int b = bid >> 5, c = bid & 31;

  if (bid == 0 && t < 128) gstat[t] = 0.f;   // zero BN accumulators (ws is poisoned)

  for (int i = t; i < 3072; i += 256) {       // coalesced W loads
    int r = i / 96, k = i - r * 96;
    wl[k][r]      = W1[i];
    wl[k][r + 32] = W2[i];
  }
  const float4* xs = (const float4*)(x + (size_t)(b * 1024 + c * 32) * 32);
  ((float4*)xl)[t] = xs[t];
  __syncthreads();

  int o = t & 63;
  int q = t >> 6;
  int m0 = q * 8;
  float acc[8][3];
#pragma unroll
  for (int m = 0; m < 8; ++m) acc[m][0] = acc[m][1] = acc[m][2] = 0.f;
#pragma unroll
  for (int f4 = 0; f4 < 8; ++f4) {
    float wv[3][4];
#pragma unroll
    for (int u = 0; u < 4; ++u) {
      int f = f4 * 4 + u;
      wv[0][u] = wl[f][o];
      wv[1][u] = wl[32 + f][o];
      wv[2][u] = wl[64 + f][o];
    }
#pragma unroll
    for (int m = 0; m < 8; ++m) {
      float4 xv = *(const float4*)&xl[m0 + m][f4 * 4];
#pragma unroll
      for (int j = 0; j < 3; ++j) {
        acc[m][j] = fmaf(xv.x, wv[j][0], acc[m][j]);
        acc[m][j] = fmaf(xv.y, wv[j][1], acc[m][j]);
        acc[m][j] = fmaf(xv.z, wv[j][2], acc[m][j]);
        acc[m][j] = fmaf(xv.w, wv[j][3], acc[m][j]);
      }
    }
  }
  unsigned pk[12];
#pragma unroll
  for (int i = 0; i < 12; ++i) {
    unsigned short lo = f2bf(acc[(2 * i) / 3][(2 * i) % 3]);
    unsigned short hi = f2bf(acc[(2 * i + 1) / 3][(2 * i + 1) % 3]);
    pk[i] = (unsigned)lo | ((unsigned)hi << 16);
  }
  int ks = c >> 2;
  int kb = (c & 3) * 192 + q * 48;            // byte base within 768B row
  int swz = (o & 7) << 4;
  unsigned char* ob = bt + (size_t)(b * 8 + ks) * 49152 + (size_t)o * 768;
  *(uint4*)(ob + ((kb     ) ^ swz)) = make_uint4(pk[0], pk[1], pk[2],  pk[3]);
  *(uint4*)(ob + ((kb + 16) ^ swz)) = make_uint4(pk[4], pk[5], pk[6],  pk[7]);
  *(uint4*)(ob + ((kb + 32) ^ swz)) = make_uint4(pk[8], pk[9], pk[10], pk[11]);
}

// ---------------- K1: async-LDS GEMM, wave-private A ring, ONE barrier -------------
// grid 1024 (128 mtiles x 8 ksplits), block 256 (4 waves). BM=64, BN=64, BK=32.
// LDS: A rings 4 waves x 4 slots x 2KB @0..32768 (wave-private!), B 48KB @32768.
// After the single post-B-stage barrier, waves free-run with counted vmcnt.
__global__ void __launch_bounds__(256, 2) k1_gemm(const float* __restrict__ A,
    const unsigned char* __restrict__ BTS, float* __restrict__ parts) {
  __shared__ __align__(16) unsigned char smem[81920];
  int t = threadIdx.x;
  int w = t >> 6, l = t & 63;
  int lr = l & 15, lg = l >> 4;
  int bid = blockIdx.x;
  int ks = bid & 7, mt = bid >> 3;
  int b = mt >> 4;
  int r0 = mt * 64;

  // ---- stage all of B (12 linear wave-instructions, shared across waves) ----
  const unsigned char* bsrc = BTS + (size_t)(b * 8 + ks) * 49152 + w * 1024 + l * 16;
#pragma unroll
  for (int i = 0; i < 12; ++i)
    async_g2l16(bsrc + i * 4096, smem + 32768 + i * 4096 + w * 1024);

  // ---- wave-private A ring: wave w stages ONLY rows [w*16, w*16+16) ----
  int rsub = l >> 3;                                   // 0..7
  int insw = ((l & 7) ^ rsub) << 4;                    // pre-swizzled source chunk
  const unsigned char* ab =
      (const unsigned char*)(A + (size_t)(r0 + w * 16) * 3072 + ks * 384);
  const unsigned char* asrc0 = ab + (size_t)rsub * 12288 + insw;        // rows 0..7
  const unsigned char* asrc1 = ab + (size_t)(rsub + 8) * 12288 + insw;  // rows 8..15
  unsigned char* aring = smem + w * 8192;

#define STAGE_A(S) { unsigned char* sl = aring + ((S) & 3) * 2048; \
    async_g2l16(asrc0 + (S) * 128, sl); \
    async_g2l16(asrc1 + (S) * 128, sl + 1024); }

  fx4 acc0 = {0.f,0.f,0.f,0.f}, acc1 = {0.f,0.f,0.f,0.f};
  fx4 acc2 = {0.f,0.f,0.f,0.f}, acc3 = {0.f,0.f,0.f,0.f};

  int sw = (lr & 7) << 4;
  const unsigned char* blp = smem + 32768 + lr * 768;

#define READ_MFMA(S) { \
    const unsigned char* sl = aring + ((S) & 3) * 2048 + lr * 128; \
    float4 a0 = *(const float4*)(sl + ((lg * 32     ) ^ sw)); \
    float4 a1 = *(const float4*)(sl + ((lg * 32 + 16) ^ sw)); \
    bh8 av = pack8(a0, a1); \
    int kb = (S) * 64 + lg * 16; \
    bh8 b0 = *(const bh8*)(blp +     0 + (kb ^ sw)); \
    bh8 b1 = *(const bh8*)(blp + 12288 + (kb ^ sw)); \
    bh8 b2 = *(const bh8*)(blp + 24576 + (kb ^ sw)); \
    bh8 b3 = *(const bh8*)(blp + 36864 + (kb ^ sw)); \
    acc0 = __builtin_amdgcn_mfma_f32_16x16x32_bf16(av, b0, acc0, 0, 0, 0); \
    acc1 = __builtin_amdgcn_mfma_f32_16x16x32_bf16(av, b1, acc1, 0, 0, 0); \
    acc2 = __builtin_amdgcn_mfma_f32_16x16x32_bf16(av, b2, acc2, 0, 0, 0); \
    acc3 = __builtin_amdgcn_mfma_f32_16x16x32_bf16(av, b3, acc3, 0, 0, 0); }

#define KSTEP(S, N) { STAGE_A((S) + 3); \
    asm volatile("s_waitcnt vmcnt(" #N ")" ::: "memory"); \
    __builtin_amdgcn_sched_barrier(0); \
    READ_MFMA(S); }

#define KSTEPN(S, N) { \
    asm volatile("s_waitcnt vmcnt(" #N ")" ::: "memory"); \
    __builtin_amdgcn_sched_barrier(0); \
    READ_MFMA(S); }

  STAGE_A(0); STAGE_A(1); STAGE_A(2);
  // wait: my 12 B-loads done (leaves my 6 A-loads in flight), then sync waves once
  asm volatile("s_waitcnt vmcnt(6)" ::: "memory");
  __builtin_amdgcn_s_barrier();
  __builtin_amdgcn_sched_barrier(0);

  KSTEP(0, 6)  KSTEP(1, 6)  KSTEP(2, 6)  KSTEP(3, 6)  KSTEP(4, 6)
  KSTEP(5, 6)  KSTEP(6, 6)  KSTEP(7, 6)  KSTEP(8, 6)
  KSTEPN(9, 4) KSTEPN(10, 2) KSTEPN(11, 0)

#undef STAGE_A
#undef READ_MFMA
#undef KSTEP
#undef KSTEPN

  // D frag: col = lane&15 (o within o-tile), row = (lane>>4)*4 + reg
  float* pout = parts + ((size_t)ks * 8192 + (size_t)(r0 + w * 16)) * 64;
#pragma unroll
  for (int r = 0; r < 4; ++r) {
    int ro = (lg * 4 + r) * 64 + lr;
    pout[ro]      = acc0[r];
    pout[ro + 16] = acc1[r];
    pout[ro + 32] = acc2[r];
    pout[ro + 48] = acc3[r];
  }
}

// ---------------- K2: sum 8 partials + bias + relu -> z, atomic BN sums ------------
__global__ void __launch_bounds__(256) k2_red(const float* __restrict__ parts,
    const float* __restrict__ b1, const float* __restrict__ b2,
    float* __restrict__ z, float* __restrict__ gstat) {
  __shared__ float4 redA[4][16], redB[4][16];
  int t = threadIdx.x, bid = blockIdx.x;
  int w = t >> 6, l = t & 63;
  int o0 = (t & 15) * 4;
  float4 bias = (o0 < 32) ? ((const float4*)b1)[o0 >> 2]
                          : ((const float4*)b2)[(o0 - 32) >> 2];
  bool rl = (o0 < 32);
  const float4* p0 = (const float4*)parts;
  int i4 = bid * 256 + t;
  float4 v = p0[i4];
#pragma unroll
  for (int j = 1; j < 8; ++j) {
    float4 vj = p0[j * 131072 + i4];
    v.x += vj.x; v.y += vj.y; v.z += vj.z; v.w += vj.w;
  }
  v.x += bias.x; v.y += bias.y; v.z += bias.z; v.w += bias.w;
  if (rl) {
    v.x = fmaxf(v.x, 0.f); v.y = fmaxf(v.y, 0.f);
    v.z = fmaxf(v.z, 0.f); v.w = fmaxf(v.w, 0.f);
  }
  ((float4*)z)[i4] = v;
  float4 s1 = v;
  float4 s2 = make_float4(v.x * v.x, v.y * v.y, v.z * v.z, v.w * v.w);
#define RED_(c) { s1.c += __shfl_xor(s1.c, 16); s1.c += __shfl_xor(s1.c, 32); \
                  s2.c += __shfl_xor(s2.c, 16); s2.c += __shfl_xor(s2.c, 32); }
  RED_(x) RED_(y) RED_(z) RED_(w)
#undef RED_
  if (l < 16) { redA[w][l] = s1; redB[w][l] = s2; }
  __syncthreads();
  if (t < 16) {
    float4 S = redA[0][t], Q = redB[0][t];
#pragma unroll
    for (int wv = 1; wv < 4; ++wv) {
      float4 a = redA[wv][t], q = redB[wv][t];
      S.x += a.x; S.y += a.y; S.z += a.z; S.w += a.w;
      Q.x += q.x; Q.y += q.y; Q.z += q.z; Q.w += q.w;
    }
    int ob = t * 4;
    atomicAdd(&gstat[ob + 0], S.x); atomicAdd(&gstat[64 + ob + 0], Q.x);
    atomicAdd(&gstat[ob + 1], S.y); atomicAdd(&gstat[64 + ob + 1], Q.y);
    atomicAdd(&gstat[ob + 2], S.z); atomicAdd(&gstat[64 + ob + 2], Q.z);
    atomicAdd(&gstat[ob + 3], S.w); atomicAdd(&gstat[64 + ob + 3], Q.w);
  }
}

// ---------------- K4: redundant per-block scale/shift + normalize in place ---------
__global__ void __launch_bounds__(256) k4_norm(const float* __restrict__ gstat,
    const float* __restrict__ gamma, const float* __restrict__ beta,
    float* __restrict__ z) {
  __shared__ float2 sstat[64];
  int t = threadIdx.x, bid = blockIdx.x;
  if (t < 64) {
    float mean = gstat[t] * (1.0f / 8192.0f);
    float var = fmaxf(gstat[64 + t] * (1.0f / 8192.0f) - mean * mean, 0.f);
    float rstd = rsqrtf(var + 1e-5f);
    float scale = gamma[t] * rstd;
    sstat[t] = make_float2(scale, beta[t] - mean * scale);
  }
  __syncthreads();
  int i4 = bid * 256 + t;
  int o0 = (t & 15) * 4;
  float2 s0 = sstat[o0], s1 = sstat[o0 + 1], s2 = sstat[o0 + 2], s3 = sstat[o0 + 3];
  float4 v = ((const float4*)z)[i4];
  v.x = v.x * s0.x + s0.y;
  v.y = v.y * s1.x + s1.y;
  v.z = v.z * s2.x + s2.y;
  v.w = v.w * s3.x + s3.y;
  ((float4*)z)[i4] = v;
}

extern "C" void kernel_launch(void* const* d_in, const int* in_sizes, int n_in,
                              void* d_out, int out_size, void* d_ws, size_t ws_size,
                              hipStream_t stream) {
  const float* WW = (const float*)d_in[0];
  const float* x  = (const float*)d_in[1];
  const float* W1 = (const float*)d_in[2];
  const float* b1 = (const float*)d_in[3];
  const float* W2 = (const float*)d_in[4];
  const float* b2 = (const float*)d_in[5];
  const float* gamma = (const float*)d_in[6];
  const float* beta  = (const float*)d_in[7];

  unsigned char* bt = (unsigned char*)d_ws;                   //  3,145,728 B
  float* parts = (float*)((char*)d_ws + 3145728);             // 16,777,216 B
  float* gstat = (float*)((char*)d_ws + 3145728 + 16777216);  //        512 B
  float* z = (float*)d_out;

  hipLaunchKernelGGL(k0_bt,   dim3(256),  dim3(256), 0, stream, x, W1, W2, bt, gstat);
  hipLaunchKernelGGL(k1_gemm, dim3(1024), dim3(256), 0, stream, WW, bt, parts);
  hipLaunchKernelGGL(k2_red,  dim3(512),  dim3(256), 0, stream, parts, b1, b2, z, gstat);
  hipLaunchKernelGGL(k4_norm, dim3(512),  dim3(256), 0, stream, gstat, gamma, beta, z);
}